// Round 2
// baseline (3303.798 us; speedup 1.0000x reference)
//
#include <hip/hip_runtime.h>
#include <hip/hip_bf16.h>

#define NN 100000
#define DD 64
#define EE 400000
#define TT 5

#define SCAN_TOTAL 500000   /* T*N */
#define SCAN_T 256
#define SCAN_PER 1024       /* 256 threads x 4 elems */
#define SCAN_B 512          /* 512*1024 = 524288 >= 500000 */

typedef __bf16 bf16x8 __attribute__((ext_vector_type(8)));
typedef float  f32x4  __attribute__((ext_vector_type(4)));

// ws layout (bytes)
#define OFF_XBF 0u            // N*D ushort        = 12,800,000
#define OFF_WT  12800000u     // T*64*128 ushort   = 81,920
#define OFF_CNT 12881920u     // T*N u32           = 2,000,000
#define OFF_WGT 14881920u     // T f32 (pad 64)
#define OFF_CUR 14881984u     // 524288 u32        = 2,097,152
#define OFF_BS  16979136u     // 512 u32
#define OFF_BO  16981184u     // 512 u32
#define OFF_SRT 16983232u     // 2M int2           = 16,000,000
#define OFF_SCL 32983232u     // 2M f32            =  8,000,000

__device__ __forceinline__ unsigned short f2bf(float f) {
    union { float f; unsigned u; } v; v.f = f;
    unsigned u = v.u;
    return (unsigned short)((u + 0x7FFFu + ((u >> 16) & 1u)) >> 16);  // RNE
}

// ---------------- Phase 1: init / convert ----------------
__global__ void k_init(const float* __restrict__ x, const float* __restrict__ W,
                       const float* __restrict__ ea,
                       unsigned short* __restrict__ xbf, unsigned short* __restrict__ wT,
                       unsigned* __restrict__ counts, float* __restrict__ wgt,
                       float* __restrict__ out) {
    int i = blockIdx.x * blockDim.x + threadIdx.x;   // grid covers N*D exactly
    if (i < NN * DD) {
        out[i] = 0.0f;
        xbf[i] = f2bf(x[i]);
    }
    if (i < TT * NN) counts[i] = 0u;
    if (i < TT * 128 * 64) {
        int t = i >> 13;          // /8192
        int rem = i & 8191;
        int d = rem >> 7;         // /128
        int k = rem & 127;
        wT[i] = f2bf(W[t * 8192 + k * 64 + d]);   // wT[t][d][k] = W[t][k][d]
    }
    if (i == 0) {
        float m = -1e30f;
        for (int t = 0; t < TT; t++) m = fmaxf(m, ea[t]);
        float e[TT]; float s = 0.0f;
        for (int t = 0; t < TT; t++) { e[t] = __expf(ea[t] - m); s += e[t]; }
        for (int t = 0; t < TT; t++) wgt[t] = e[t] / s;
    }
}

// ---------------- Phase 2: per-(t,src) degree ----------------
__global__ void k_count(const int* __restrict__ edges, unsigned* __restrict__ counts) {
    int i = blockIdx.x * blockDim.x + threadIdx.x;
    if (i >= TT * EE) return;
    int t = i / EE;
    int e = i - t * EE;
    int s = edges[(size_t)t * 2 * EE + e];          // src row
    atomicAdd(&counts[t * NN + s], 1u);
}

// ---------------- Phase 2b: exclusive scan of counts (3 kernels) ----------------
__global__ void k_scan1(const unsigned* __restrict__ cnt, unsigned* __restrict__ cur,
                        unsigned* __restrict__ bsum) {
    __shared__ unsigned s[SCAN_T];
    const int b = blockIdx.x, tid = threadIdx.x;
    const int base = b * SCAN_PER + tid * 4;
    uint4 v = make_uint4(0u, 0u, 0u, 0u);
    if (base + 3 < SCAN_TOTAL) {
        v = *reinterpret_cast<const uint4*>(cnt + base);
    } else {
        if (base + 0 < SCAN_TOTAL) v.x = cnt[base + 0];
        if (base + 1 < SCAN_TOTAL) v.y = cnt[base + 1];
        if (base + 2 < SCAN_TOTAL) v.z = cnt[base + 2];
        if (base + 3 < SCAN_TOTAL) v.w = cnt[base + 3];
    }
    const unsigned tsum = v.x + v.y + v.z + v.w;
    s[tid] = tsum;
    __syncthreads();
    unsigned inc = tsum;
    for (int d = 1; d < SCAN_T; d <<= 1) {
        unsigned add = (tid >= d) ? s[tid - d] : 0u;
        __syncthreads();
        inc += add;
        s[tid] = inc;
        __syncthreads();
    }
    if (tid == SCAN_T - 1) bsum[b] = inc;
    const unsigned p0 = inc - tsum;
    const unsigned p1 = p0 + v.x, p2 = p1 + v.y, p3 = p2 + v.z;
    if (base + 3 < SCAN_TOTAL) {
        *reinterpret_cast<uint4*>(cur + base) = make_uint4(p0, p1, p2, p3);
    } else {
        if (base + 0 < SCAN_TOTAL) cur[base + 0] = p0;
        if (base + 1 < SCAN_TOTAL) cur[base + 1] = p1;
        if (base + 2 < SCAN_TOTAL) cur[base + 2] = p2;
        if (base + 3 < SCAN_TOTAL) cur[base + 3] = p3;
    }
}

__global__ void k_scan2(const unsigned* __restrict__ bsum, unsigned* __restrict__ boff) {
    __shared__ unsigned s[SCAN_B];
    const int tid = threadIdx.x;
    const unsigned v = bsum[tid];
    s[tid] = v;
    __syncthreads();
    unsigned inc = v;
    for (int d = 1; d < SCAN_B; d <<= 1) {
        unsigned add = (tid >= d) ? s[tid - d] : 0u;
        __syncthreads();
        inc += add;
        s[tid] = inc;
        __syncthreads();
    }
    boff[tid] = inc - v;
}

__global__ void k_scan3(unsigned* __restrict__ cur, const unsigned* __restrict__ boff) {
    const int b = blockIdx.x, tid = threadIdx.x;
    const int base = b * SCAN_PER + tid * 4;
    const unsigned o = boff[b];
    if (base + 3 < SCAN_TOTAL) {
        uint4 v = *reinterpret_cast<uint4*>(cur + base);
        v.x += o; v.y += o; v.z += o; v.w += o;
        *reinterpret_cast<uint4*>(cur + base) = v;
    } else {
        if (base + 0 < SCAN_TOTAL) cur[base + 0] += o;
        if (base + 1 < SCAN_TOTAL) cur[base + 1] += o;
        if (base + 2 < SCAN_TOTAL) cur[base + 2] += o;
        if (base + 3 < SCAN_TOTAL) cur[base + 3] += o;
    }
}

// ---------------- Phase 2c: scatter edges into src-sorted order ----------------
__global__ void k_fill(const int* __restrict__ edges, unsigned* __restrict__ cur,
                       const unsigned* __restrict__ cnt, const float* __restrict__ wgt,
                       int2* __restrict__ sorted, float* __restrict__ scl) {
    int i = blockIdx.x * blockDim.x + threadIdx.x;
    if (i >= TT * EE) return;
    int t = i / EE;
    int e = i - t * EE;
    int s = edges[(size_t)t * 2 * EE + e];
    int d = edges[(size_t)t * 2 * EE + EE + e];
    unsigned pos = atomicAdd(&cur[t * NN + s], 1u);
    sorted[pos] = make_int2(s, d);
    scl[pos] = wgt[t] / (float)cnt[t * NN + s];
}

// ---------------- Phase 3: gather -> MFMA -> segmented scatter-mean ----------------
__global__ __launch_bounds__(256) void k_edge(
    const unsigned short* __restrict__ xbf, const unsigned short* __restrict__ wT,
    const float* __restrict__ b, const int2* __restrict__ sorted,
    const float* __restrict__ scl, float* __restrict__ out) {
    const int t  = blockIdx.y;
    const int e0 = blockIdx.x * 128;

    __shared__ __align__(16) unsigned short Ab[128][136];   // feats tile; reused as f32 proj[128][68]
    __shared__ __align__(16) unsigned short Bb[64][136];    // W_t^T [d][k]
    __shared__ float scale_s[128];
    __shared__ int   src_s[128];

    const int tid = threadIdx.x;

    // stage B: W_t^T is 64x128 bf16 contiguous in ws
    {
        const unsigned short* src = wT + (size_t)t * 8192;
        int d = tid >> 2, seg = tid & 3;                       // 64B per thread
        const float4* g = reinterpret_cast<const float4*>(src + d * 128 + seg * 32);
        float4* l = reinterpret_cast<float4*>(&Bb[d][seg * 32]);
#pragma unroll
        for (int c = 0; c < 4; c++) l[c] = g[c];
    }
    // stage A: gather x rows (bf16, 128B each); thread pair per sorted edge
    {
        int e = tid >> 1, half = tid & 1;
        int2 sd = sorted[(size_t)t * EE + e0 + e];
        int idx = half ? sd.y : sd.x;
        const float4* g = reinterpret_cast<const float4*>(xbf + (size_t)idx * 64);
        float4* l = reinterpret_cast<float4*>(&Ab[e][half * 64]);
#pragma unroll
        for (int c = 0; c < 8; c++) l[c] = g[c];
        if (half == 0) {
            src_s[e] = sd.x;
            scale_s[e] = scl[(size_t)t * EE + e0 + e];
        }
    }
    __syncthreads();

    const int wv = tid >> 6, lane = tid & 63;
    const int m16 = lane & 15, quad = lane >> 4;

    f32x4 acc[2][4];
#pragma unroll
    for (int tm = 0; tm < 2; tm++)
#pragma unroll
        for (int tn = 0; tn < 4; tn++)
            acc[tm][tn] = (f32x4){0.f, 0.f, 0.f, 0.f};

#pragma unroll
    for (int kk = 0; kk < 128; kk += 32) {
        const int kb = kk + quad * 8;
        bf16x8 af[2], bfr[4];
#pragma unroll
        for (int tm = 0; tm < 2; tm++)
            af[tm] = *reinterpret_cast<const bf16x8*>(&Ab[wv * 32 + tm * 16 + m16][kb]);
#pragma unroll
        for (int tn = 0; tn < 4; tn++)
            bfr[tn] = *reinterpret_cast<const bf16x8*>(&Bb[tn * 16 + m16][kb]);
#pragma unroll
        for (int tm = 0; tm < 2; tm++)
#pragma unroll
            for (int tn = 0; tn < 4; tn++)
                acc[tm][tn] = __builtin_amdgcn_mfma_f32_16x16x32_bf16(
                    af[tm], bfr[tn], acc[tm][tn], 0, 0, 0);
    }

    // all waves done reading Ab before we overwrite it with f32 proj
    __syncthreads();

    float bias[4];
#pragma unroll
    for (int tn = 0; tn < 4; tn++) bias[tn] = b[t * 64 + tn * 16 + m16];

    float* proj = reinterpret_cast<float*>(&Ab[0][0]);   // [128][68] f32, stride 68
#pragma unroll
    for (int tm = 0; tm < 2; tm++) {
#pragma unroll
        for (int r = 0; r < 4; r++) {
            const int eloc = wv * 32 + tm * 16 + quad * 4 + r;
            const float s = scale_s[eloc];
#pragma unroll
            for (int tn = 0; tn < 4; tn++) {
                float v = acc[tm][tn][r] + bias[tn];
                v = v > 0.f ? v : 0.f;
                proj[eloc * 68 + tn * 16 + m16] = v * s;
            }
        }
    }
    __syncthreads();

    // segmented reduce: one atomicAdd set per distinct src in the tile
    {
        const int e = tid >> 1, half = tid & 1;
        const int my_src = src_s[e];
        const bool head = (e == 0) || (src_s[e - 1] != my_src);
        if (head) {
            f32x4 sum[8];
#pragma unroll
            for (int c = 0; c < 8; c++) sum[c] = (f32x4){0.f, 0.f, 0.f, 0.f};
            int j = e;
            do {
                const float* row = proj + j * 68 + half * 32;
#pragma unroll
                for (int cc = 0; cc < 8; cc++) {
                    int c = (cc + (e & 7)) & 7;   // rotate to spread LDS banks
                    sum[c] += *reinterpret_cast<const f32x4*>(row + c * 4);
                }
                j++;
            } while (j < 128 && src_s[j] == my_src);
            float* orow = out + (size_t)my_src * 64 + half * 32;
#pragma unroll
            for (int c = 0; c < 8; c++) {
                atomicAdd(orow + c * 4 + 0, sum[c][0]);
                atomicAdd(orow + c * 4 + 1, sum[c][1]);
                atomicAdd(orow + c * 4 + 2, sum[c][2]);
                atomicAdd(orow + c * 4 + 3, sum[c][3]);
            }
        }
    }
}

extern "C" void kernel_launch(void* const* d_in, const int* in_sizes, int n_in,
                              void* d_out, int out_size, void* d_ws, size_t ws_size,
                              hipStream_t stream) {
    const float* x     = (const float*)d_in[0];
    const float* W     = (const float*)d_in[1];
    const float* b     = (const float*)d_in[2];
    const float* ea    = (const float*)d_in[3];
    const int*   edges = (const int*)d_in[4];
    float* out = (float*)d_out;

    char* ws = (char*)d_ws;
    unsigned short* xbf = (unsigned short*)(ws + OFF_XBF);
    unsigned short* wT  = (unsigned short*)(ws + OFF_WT);
    unsigned* counts    = (unsigned*)(ws + OFF_CNT);
    float* wgt          = (float*)(ws + OFF_WGT);
    unsigned* cur       = (unsigned*)(ws + OFF_CUR);
    unsigned* bsum      = (unsigned*)(ws + OFF_BS);
    unsigned* boff      = (unsigned*)(ws + OFF_BO);
    int2* sorted        = (int2*)(ws + OFF_SRT);
    float* scl          = (float*)(ws + OFF_SCL);

    // Phase 1: out-zero, x->bf16, counts-zero, W^T, softmax
    k_init<<<(NN * DD) / 256, 256, 0, stream>>>(x, W, ea, xbf, wT, counts, wgt, out);

    // Phase 2: degree counts
    k_count<<<(TT * EE + 255) / 256, 256, 0, stream>>>(edges, counts);

    // Phase 2b: exclusive scan counts -> cur
    k_scan1<<<SCAN_B, SCAN_T, 0, stream>>>(counts, cur, bsum);
    k_scan2<<<1, SCAN_B, 0, stream>>>(bsum, boff);
    k_scan3<<<SCAN_B, SCAN_T, 0, stream>>>(cur, boff);

    // Phase 2c: counting-sort edges by (t, src)
    k_fill<<<(TT * EE + 255) / 256, 256, 0, stream>>>(edges, cur, counts, wgt, sorted, scl);

    // Phase 3: MFMA gather-GEMM + segmented scatter; one block = 1 t x 128 sorted edges
    dim3 grid(EE / 128, TT);
    k_edge<<<grid, 256, 0, stream>>>(xbf, wT, b, sorted, scl, out);
}

// Round 3
// 2235.766 us; speedup vs baseline: 1.4777x; 1.4777x over previous
//
#include <hip/hip_runtime.h>
#include <hip/hip_bf16.h>

#define NN 100000
#define DD 64
#define EE 400000
#define TT 5

#define SCAN_TOTAL 500000   /* T*N */
#define SCAN_T 256
#define SCAN_PER 1024       /* 256 threads x 4 elems */
#define SCAN_B 512          /* 512*1024 = 524288 >= 500000 */

typedef __bf16 bf16x8 __attribute__((ext_vector_type(8)));
typedef float  f32x4  __attribute__((ext_vector_type(4)));

// ws layout (bytes)
#define OFF_XBF 0u            // N*D ushort        = 12,800,000
#define OFF_WT  12800000u     // T*64*128 ushort   = 81,920
#define OFF_CNT 12881920u     // T*N u32           = 2,000,000
#define OFF_WGT 14881920u     // T f32 (pad 64)
#define OFF_CUR 14881984u     // 524288 u32        = 2,097,152
#define OFF_BS  16979136u     // 512 u32
#define OFF_BO  16981184u     // 512 u32
#define OFF_SRT 16983232u     // 2M int2           = 16,000,000
#define OFF_SCL 32983232u     // 2M f32            =  8,000,000

__device__ __forceinline__ unsigned short f2bf(float f) {
    union { float f; unsigned u; } v; v.f = f;
    unsigned u = v.u;
    return (unsigned short)((u + 0x7FFFu + ((u >> 16) & 1u)) >> 16);  // RNE
}

// ---------------- Phase 1: init / convert ----------------
__global__ void k_init(const float* __restrict__ x, const float* __restrict__ W,
                       const float* __restrict__ ea,
                       unsigned short* __restrict__ xbf, unsigned short* __restrict__ wT,
                       unsigned* __restrict__ counts, float* __restrict__ wgt,
                       float* __restrict__ out) {
    int i = blockIdx.x * blockDim.x + threadIdx.x;   // grid covers N*D exactly
    if (i < NN * DD) {
        out[i] = 0.0f;
        xbf[i] = f2bf(x[i]);
    }
    if (i < TT * NN) counts[i] = 0u;
    if (i < TT * 128 * 64) {
        int t = i >> 13;          // /8192
        int rem = i & 8191;
        int d = rem >> 7;         // /128
        int k = rem & 127;
        wT[i] = f2bf(W[t * 8192 + k * 64 + d]);   // wT[t][d][k] = W[t][k][d]
    }
    if (i == 0) {
        float m = -1e30f;
        for (int t = 0; t < TT; t++) m = fmaxf(m, ea[t]);
        float e[TT]; float s = 0.0f;
        for (int t = 0; t < TT; t++) { e[t] = __expf(ea[t] - m); s += e[t]; }
        for (int t = 0; t < TT; t++) wgt[t] = e[t] / s;
    }
}

// ---------------- Phase 2: per-(t,src) degree ----------------
__global__ void k_count(const int* __restrict__ edges, unsigned* __restrict__ counts) {
    int i = blockIdx.x * blockDim.x + threadIdx.x;
    if (i >= TT * EE) return;
    int t = i / EE;
    int e = i - t * EE;
    int s = edges[(size_t)t * 2 * EE + e];          // src row
    atomicAdd(&counts[t * NN + s], 1u);
}

// ---------------- Phase 2b: exclusive scan of counts (3 kernels) ----------------
__global__ void k_scan1(const unsigned* __restrict__ cnt, unsigned* __restrict__ cur,
                        unsigned* __restrict__ bsum) {
    __shared__ unsigned s[SCAN_T];
    const int b = blockIdx.x, tid = threadIdx.x;
    const int base = b * SCAN_PER + tid * 4;
    uint4 v = make_uint4(0u, 0u, 0u, 0u);
    if (base + 3 < SCAN_TOTAL) {
        v = *reinterpret_cast<const uint4*>(cnt + base);
    } else {
        if (base + 0 < SCAN_TOTAL) v.x = cnt[base + 0];
        if (base + 1 < SCAN_TOTAL) v.y = cnt[base + 1];
        if (base + 2 < SCAN_TOTAL) v.z = cnt[base + 2];
        if (base + 3 < SCAN_TOTAL) v.w = cnt[base + 3];
    }
    const unsigned tsum = v.x + v.y + v.z + v.w;
    s[tid] = tsum;
    __syncthreads();
    unsigned inc = tsum;
    for (int d = 1; d < SCAN_T; d <<= 1) {
        unsigned add = (tid >= d) ? s[tid - d] : 0u;
        __syncthreads();
        inc += add;
        s[tid] = inc;
        __syncthreads();
    }
    if (tid == SCAN_T - 1) bsum[b] = inc;
    const unsigned p0 = inc - tsum;
    const unsigned p1 = p0 + v.x, p2 = p1 + v.y, p3 = p2 + v.z;
    if (base + 3 < SCAN_TOTAL) {
        *reinterpret_cast<uint4*>(cur + base) = make_uint4(p0, p1, p2, p3);
    } else {
        if (base + 0 < SCAN_TOTAL) cur[base + 0] = p0;
        if (base + 1 < SCAN_TOTAL) cur[base + 1] = p1;
        if (base + 2 < SCAN_TOTAL) cur[base + 2] = p2;
        if (base + 3 < SCAN_TOTAL) cur[base + 3] = p3;
    }
}

__global__ void k_scan2(const unsigned* __restrict__ bsum, unsigned* __restrict__ boff) {
    __shared__ unsigned s[SCAN_B];
    const int tid = threadIdx.x;
    const unsigned v = bsum[tid];
    s[tid] = v;
    __syncthreads();
    unsigned inc = v;
    for (int d = 1; d < SCAN_B; d <<= 1) {
        unsigned add = (tid >= d) ? s[tid - d] : 0u;
        __syncthreads();
        inc += add;
        s[tid] = inc;
        __syncthreads();
    }
    boff[tid] = inc - v;
}

__global__ void k_scan3(unsigned* __restrict__ cur, const unsigned* __restrict__ boff) {
    const int b = blockIdx.x, tid = threadIdx.x;
    const int base = b * SCAN_PER + tid * 4;
    const unsigned o = boff[b];
    if (base + 3 < SCAN_TOTAL) {
        uint4 v = *reinterpret_cast<uint4*>(cur + base);
        v.x += o; v.y += o; v.z += o; v.w += o;
        *reinterpret_cast<uint4*>(cur + base) = v;
    } else {
        if (base + 0 < SCAN_TOTAL) cur[base + 0] += o;
        if (base + 1 < SCAN_TOTAL) cur[base + 1] += o;
        if (base + 2 < SCAN_TOTAL) cur[base + 2] += o;
        if (base + 3 < SCAN_TOTAL) cur[base + 3] += o;
    }
}

// ---------------- Phase 2c: scatter edges into src-sorted order ----------------
__global__ void k_fill(const int* __restrict__ edges, unsigned* __restrict__ cur,
                       const unsigned* __restrict__ cnt, const float* __restrict__ wgt,
                       int2* __restrict__ sorted, float* __restrict__ scl) {
    int i = blockIdx.x * blockDim.x + threadIdx.x;
    if (i >= TT * EE) return;
    int t = i / EE;
    int e = i - t * EE;
    int s = edges[(size_t)t * 2 * EE + e];
    int d = edges[(size_t)t * 2 * EE + EE + e];
    unsigned pos = atomicAdd(&cur[t * NN + s], 1u);
    sorted[pos] = make_int2(s, d);
    scl[pos] = wgt[t] / (float)cnt[t * NN + s];
}

// ---------------- Phase 3: gather -> MFMA -> segmented scatter-mean ----------------
__global__ __launch_bounds__(256) void k_edge(
    const unsigned short* __restrict__ xbf, const unsigned short* __restrict__ wT,
    const float* __restrict__ b, const int2* __restrict__ sorted,
    const float* __restrict__ scl, float* __restrict__ out) {
    const int t  = blockIdx.y;
    const int e0 = blockIdx.x * 128;

    __shared__ __align__(16) unsigned short Ab[128][136];   // feats tile; reused as f32 proj[128][68]
    __shared__ __align__(16) unsigned short Bb[64][136];    // W_t^T [d][k]
    __shared__ float scale_s[128];
    __shared__ int   src_s[128];

    const int tid = threadIdx.x;

    // stage B: W_t^T is 64x128 bf16 contiguous in ws
    {
        const unsigned short* src = wT + (size_t)t * 8192;
        int d = tid >> 2, seg = tid & 3;                       // 64B per thread
        const float4* g = reinterpret_cast<const float4*>(src + d * 128 + seg * 32);
        float4* l = reinterpret_cast<float4*>(&Bb[d][seg * 32]);
#pragma unroll
        for (int c = 0; c < 4; c++) l[c] = g[c];
    }
    // stage A: gather x rows (bf16, 128B each); thread pair per sorted edge
    {
        int e = tid >> 1, half = tid & 1;
        int2 sd = sorted[(size_t)t * EE + e0 + e];
        int idx = half ? sd.y : sd.x;
        const float4* g = reinterpret_cast<const float4*>(xbf + (size_t)idx * 64);
        float4* l = reinterpret_cast<float4*>(&Ab[e][half * 64]);
#pragma unroll
        for (int c = 0; c < 8; c++) l[c] = g[c];
        if (half == 0) {
            src_s[e] = sd.x;
            scale_s[e] = scl[(size_t)t * EE + e0 + e];
        }
    }
    __syncthreads();

    const int wv = tid >> 6, lane = tid & 63;
    const int m16 = lane & 15, quad = lane >> 4;

    f32x4 acc[2][4];
#pragma unroll
    for (int tm = 0; tm < 2; tm++)
#pragma unroll
        for (int tn = 0; tn < 4; tn++)
            acc[tm][tn] = (f32x4){0.f, 0.f, 0.f, 0.f};

#pragma unroll
    for (int kk = 0; kk < 128; kk += 32) {
        const int kb = kk + quad * 8;
        bf16x8 af[2], bfr[4];
#pragma unroll
        for (int tm = 0; tm < 2; tm++)
            af[tm] = *reinterpret_cast<const bf16x8*>(&Ab[wv * 32 + tm * 16 + m16][kb]);
#pragma unroll
        for (int tn = 0; tn < 4; tn++)
            bfr[tn] = *reinterpret_cast<const bf16x8*>(&Bb[tn * 16 + m16][kb]);
#pragma unroll
        for (int tm = 0; tm < 2; tm++)
#pragma unroll
            for (int tn = 0; tn < 4; tn++)
                acc[tm][tn] = __builtin_amdgcn_mfma_f32_16x16x32_bf16(
                    af[tm], bfr[tn], acc[tm][tn], 0, 0, 0);
    }

    // all waves done reading Ab before we overwrite it with f32 proj
    __syncthreads();

    float bias[4];
#pragma unroll
    for (int tn = 0; tn < 4; tn++) bias[tn] = b[t * 64 + tn * 16 + m16];

    float* proj = reinterpret_cast<float*>(&Ab[0][0]);   // [128][68] f32, stride 68
#pragma unroll
    for (int tm = 0; tm < 2; tm++) {
#pragma unroll
        for (int r = 0; r < 4; r++) {
            const int eloc = wv * 32 + tm * 16 + quad * 4 + r;
            const float s = scale_s[eloc];
#pragma unroll
            for (int tn = 0; tn < 4; tn++) {
                float v = acc[tm][tn][r] + bias[tn];
                v = v > 0.f ? v : 0.f;
                proj[eloc * 68 + tn * 16 + m16] = v * s;
            }
        }
    }
    __syncthreads();

    // segmented reduce: one atomicAdd set per distinct src in the tile.
    // NOTE: sum[] indexing MUST be compile-time static — dynamic indexing
    // spilled it to scratch in R2 (WRITE_SIZE 1 GB, 8x regression).
    {
        const int e = tid >> 1, half = tid & 1;
        const int my_src = src_s[e];
        const bool head = (e == 0) || (src_s[e - 1] != my_src);
        if (head) {
            f32x4 sum[8];
#pragma unroll
            for (int c = 0; c < 8; c++) sum[c] = (f32x4){0.f, 0.f, 0.f, 0.f};
            int j = e;
            do {
                const float* row = proj + j * 68 + half * 32;
#pragma unroll
                for (int c = 0; c < 8; c++)
                    sum[c] += *reinterpret_cast<const f32x4*>(row + c * 4);
                j++;
            } while (j < 128 && src_s[j] == my_src);
            float* orow = out + (size_t)my_src * 64 + half * 32;
#pragma unroll
            for (int c = 0; c < 8; c++) {
                atomicAdd(orow + c * 4 + 0, sum[c][0]);
                atomicAdd(orow + c * 4 + 1, sum[c][1]);
                atomicAdd(orow + c * 4 + 2, sum[c][2]);
                atomicAdd(orow + c * 4 + 3, sum[c][3]);
            }
        }
    }
}

extern "C" void kernel_launch(void* const* d_in, const int* in_sizes, int n_in,
                              void* d_out, int out_size, void* d_ws, size_t ws_size,
                              hipStream_t stream) {
    const float* x     = (const float*)d_in[0];
    const float* W     = (const float*)d_in[1];
    const float* b     = (const float*)d_in[2];
    const float* ea    = (const float*)d_in[3];
    const int*   edges = (const int*)d_in[4];
    float* out = (float*)d_out;

    char* ws = (char*)d_ws;
    unsigned short* xbf = (unsigned short*)(ws + OFF_XBF);
    unsigned short* wT  = (unsigned short*)(ws + OFF_WT);
    unsigned* counts    = (unsigned*)(ws + OFF_CNT);
    float* wgt          = (float*)(ws + OFF_WGT);
    unsigned* cur       = (unsigned*)(ws + OFF_CUR);
    unsigned* bsum      = (unsigned*)(ws + OFF_BS);
    unsigned* boff      = (unsigned*)(ws + OFF_BO);
    int2* sorted        = (int2*)(ws + OFF_SRT);
    float* scl          = (float*)(ws + OFF_SCL);

    // Phase 1: out-zero, x->bf16, counts-zero, W^T, softmax
    k_init<<<(NN * DD) / 256, 256, 0, stream>>>(x, W, ea, xbf, wT, counts, wgt, out);

    // Phase 2: degree counts
    k_count<<<(TT * EE + 255) / 256, 256, 0, stream>>>(edges, counts);

    // Phase 2b: exclusive scan counts -> cur
    k_scan1<<<SCAN_B, SCAN_T, 0, stream>>>(counts, cur, bsum);
    k_scan2<<<1, SCAN_B, 0, stream>>>(bsum, boff);
    k_scan3<<<SCAN_B, SCAN_T, 0, stream>>>(cur, boff);

    // Phase 2c: counting-sort edges by (t, src)
    k_fill<<<(TT * EE + 255) / 256, 256, 0, stream>>>(edges, cur, counts, wgt, sorted, scl);

    // Phase 3: MFMA gather-GEMM + segmented scatter; one block = 1 t x 128 sorted edges
    dim3 grid(EE / 128, TT);
    k_edge<<<grid, 256, 0, stream>>>(xbf, wT, b, sorted, scl, out);
}

// Round 4
// 479.035 us; speedup vs baseline: 6.8968x; 4.6672x over previous
//
#include <hip/hip_runtime.h>
#include <hip/hip_bf16.h>

#define NN 100000
#define DD 64
#define EE 400000
#define TT 5

#define SCAN_TOTAL 500000   /* T*N */
#define SCAN_T 256
#define SCAN_PER 1024       /* 256 threads x 4 elems */
#define SCAN_B 512          /* 512*1024 = 524288 >= 500000 */

typedef __bf16 bf16x8 __attribute__((ext_vector_type(8)));
typedef float  f32x4  __attribute__((ext_vector_type(4)));

// ws layout (bytes)
#define OFF_XBF 0u            // N*D ushort        = 12,800,000
#define OFF_WT  12800000u     // T*64*128 ushort   = 81,920
#define OFF_CNT 12881920u     // T*N u32           = 2,000,000
#define OFF_WGT 14881920u     // T f32 (pad 64)
#define OFF_CUR 14881984u     // 524288 u32        = 2,097,152
#define OFF_BS  16979136u     // 512 u32
#define OFF_BO  16981184u     // 512 u32
#define OFF_SRT 16983232u     // 2M int2           = 16,000,000
#define OFF_SCL 32983232u     // 2M f32            =  8,000,000

__device__ __forceinline__ unsigned short f2bf(float f) {
    union { float f; unsigned u; } v; v.f = f;
    unsigned u = v.u;
    return (unsigned short)((u + 0x7FFFu + ((u >> 16) & 1u)) >> 16);  // RNE
}

// ---------------- Phase 1: init / convert ----------------
__global__ void k_init(const float* __restrict__ x, const float* __restrict__ W,
                       const float* __restrict__ ea,
                       unsigned short* __restrict__ xbf, unsigned short* __restrict__ wT,
                       unsigned* __restrict__ counts, float* __restrict__ wgt,
                       float* __restrict__ out) {
    int i = blockIdx.x * blockDim.x + threadIdx.x;   // grid covers N*D exactly
    if (i < NN * DD) {
        out[i] = 0.0f;
        xbf[i] = f2bf(x[i]);
    }
    if (i < TT * NN) counts[i] = 0u;
    if (i < TT * 128 * 64) {
        int t = i >> 13;          // /8192
        int rem = i & 8191;
        int d = rem >> 7;         // /128
        int k = rem & 127;
        wT[i] = f2bf(W[t * 8192 + k * 64 + d]);   // wT[t][d][k] = W[t][k][d]
    }
    if (i == 0) {
        float m = -1e30f;
        for (int t = 0; t < TT; t++) m = fmaxf(m, ea[t]);
        float e[TT]; float s = 0.0f;
        for (int t = 0; t < TT; t++) { e[t] = __expf(ea[t] - m); s += e[t]; }
        for (int t = 0; t < TT; t++) wgt[t] = e[t] / s;
    }
}

// ---------------- Phase 2: per-(t,src) degree ----------------
__global__ void k_count(const int* __restrict__ edges, unsigned* __restrict__ counts) {
    int i = blockIdx.x * blockDim.x + threadIdx.x;
    if (i >= TT * EE) return;
    int t = i / EE;
    int e = i - t * EE;
    int s = edges[(size_t)t * 2 * EE + e];          // src row
    atomicAdd(&counts[t * NN + s], 1u);
}

// ---------------- Phase 2b: exclusive scan of counts (3 kernels) ----------------
__global__ void k_scan1(const unsigned* __restrict__ cnt, unsigned* __restrict__ cur,
                        unsigned* __restrict__ bsum) {
    __shared__ unsigned s[SCAN_T];
    const int b = blockIdx.x, tid = threadIdx.x;
    const int base = b * SCAN_PER + tid * 4;
    uint4 v = make_uint4(0u, 0u, 0u, 0u);
    if (base + 3 < SCAN_TOTAL) {
        v = *reinterpret_cast<const uint4*>(cnt + base);
    } else {
        if (base + 0 < SCAN_TOTAL) v.x = cnt[base + 0];
        if (base + 1 < SCAN_TOTAL) v.y = cnt[base + 1];
        if (base + 2 < SCAN_TOTAL) v.z = cnt[base + 2];
        if (base + 3 < SCAN_TOTAL) v.w = cnt[base + 3];
    }
    const unsigned tsum = v.x + v.y + v.z + v.w;
    s[tid] = tsum;
    __syncthreads();
    unsigned inc = tsum;
    for (int d = 1; d < SCAN_T; d <<= 1) {
        unsigned add = (tid >= d) ? s[tid - d] : 0u;
        __syncthreads();
        inc += add;
        s[tid] = inc;
        __syncthreads();
    }
    if (tid == SCAN_T - 1) bsum[b] = inc;
    const unsigned p0 = inc - tsum;
    const unsigned p1 = p0 + v.x, p2 = p1 + v.y, p3 = p2 + v.z;
    if (base + 3 < SCAN_TOTAL) {
        *reinterpret_cast<uint4*>(cur + base) = make_uint4(p0, p1, p2, p3);
    } else {
        if (base + 0 < SCAN_TOTAL) cur[base + 0] = p0;
        if (base + 1 < SCAN_TOTAL) cur[base + 1] = p1;
        if (base + 2 < SCAN_TOTAL) cur[base + 2] = p2;
        if (base + 3 < SCAN_TOTAL) cur[base + 3] = p3;
    }
}

__global__ void k_scan2(const unsigned* __restrict__ bsum, unsigned* __restrict__ boff) {
    __shared__ unsigned s[SCAN_B];
    const int tid = threadIdx.x;
    const unsigned v = bsum[tid];
    s[tid] = v;
    __syncthreads();
    unsigned inc = v;
    for (int d = 1; d < SCAN_B; d <<= 1) {
        unsigned add = (tid >= d) ? s[tid - d] : 0u;
        __syncthreads();
        inc += add;
        s[tid] = inc;
        __syncthreads();
    }
    boff[tid] = inc - v;
}

__global__ void k_scan3(unsigned* __restrict__ cur, const unsigned* __restrict__ boff) {
    const int b = blockIdx.x, tid = threadIdx.x;
    const int base = b * SCAN_PER + tid * 4;
    const unsigned o = boff[b];
    if (base + 3 < SCAN_TOTAL) {
        uint4 v = *reinterpret_cast<uint4*>(cur + base);
        v.x += o; v.y += o; v.z += o; v.w += o;
        *reinterpret_cast<uint4*>(cur + base) = v;
    } else {
        if (base + 0 < SCAN_TOTAL) cur[base + 0] += o;
        if (base + 1 < SCAN_TOTAL) cur[base + 1] += o;
        if (base + 2 < SCAN_TOTAL) cur[base + 2] += o;
        if (base + 3 < SCAN_TOTAL) cur[base + 3] += o;
    }
}

// ---------------- Phase 2c: scatter edges into src-sorted order ----------------
__global__ void k_fill(const int* __restrict__ edges, unsigned* __restrict__ cur,
                       const unsigned* __restrict__ cnt, const float* __restrict__ wgt,
                       int2* __restrict__ sorted, float* __restrict__ scl) {
    int i = blockIdx.x * blockDim.x + threadIdx.x;
    if (i >= TT * EE) return;
    int t = i / EE;
    int e = i - t * EE;
    int s = edges[(size_t)t * 2 * EE + e];
    int d = edges[(size_t)t * 2 * EE + EE + e];
    unsigned pos = atomicAdd(&cur[t * NN + s], 1u);
    sorted[pos] = make_int2(s, d);
    scl[pos] = wgt[t] / (float)cnt[t * NN + s];
}

// ---------------- Phase 3: gather -> MFMA -> wave-cooperative segmented scatter ----------------
__global__ __launch_bounds__(256) void k_edge(
    const unsigned short* __restrict__ xbf, const unsigned short* __restrict__ wT,
    const float* __restrict__ b, const int2* __restrict__ sorted,
    const float* __restrict__ scl, float* __restrict__ out) {
    const int t  = blockIdx.y;
    const int e0 = blockIdx.x * 128;

    __shared__ __align__(16) unsigned short Ab[128][136];   // feats tile; reused as f32 proj[128][68]
    __shared__ __align__(16) unsigned short Bb[64][136];    // W_t^T [d][k]
    __shared__ float scale_s[128];
    __shared__ int   src_s[132];                             // padded; [128] unused (short-circuit guard)

    const int tid = threadIdx.x;

    // stage B: W_t^T is 64x128 bf16 contiguous in ws
    {
        const unsigned short* src = wT + (size_t)t * 8192;
        int d = tid >> 2, seg = tid & 3;                       // 64B per thread
        const float4* g = reinterpret_cast<const float4*>(src + d * 128 + seg * 32);
        float4* l = reinterpret_cast<float4*>(&Bb[d][seg * 32]);
#pragma unroll
        for (int c = 0; c < 4; c++) l[c] = g[c];
    }
    // stage A: gather x rows (bf16, 128B each); thread pair per sorted edge
    {
        int e = tid >> 1, half = tid & 1;
        int2 sd = sorted[(size_t)t * EE + e0 + e];
        int idx = half ? sd.y : sd.x;
        const float4* g = reinterpret_cast<const float4*>(xbf + (size_t)idx * 64);
        float4* l = reinterpret_cast<float4*>(&Ab[e][half * 64]);
#pragma unroll
        for (int c = 0; c < 8; c++) l[c] = g[c];
        if (half == 0) {
            src_s[e] = sd.x;
            scale_s[e] = scl[(size_t)t * EE + e0 + e];
        }
    }
    __syncthreads();

    const int wv = tid >> 6, lane = tid & 63;
    const int m16 = lane & 15, quad = lane >> 4;

    f32x4 acc[2][4];
#pragma unroll
    for (int tm = 0; tm < 2; tm++)
#pragma unroll
        for (int tn = 0; tn < 4; tn++)
            acc[tm][tn] = (f32x4){0.f, 0.f, 0.f, 0.f};

#pragma unroll
    for (int kk = 0; kk < 128; kk += 32) {
        const int kb = kk + quad * 8;
        bf16x8 af[2], bfr[4];
#pragma unroll
        for (int tm = 0; tm < 2; tm++)
            af[tm] = *reinterpret_cast<const bf16x8*>(&Ab[wv * 32 + tm * 16 + m16][kb]);
#pragma unroll
        for (int tn = 0; tn < 4; tn++)
            bfr[tn] = *reinterpret_cast<const bf16x8*>(&Bb[tn * 16 + m16][kb]);
#pragma unroll
        for (int tm = 0; tm < 2; tm++)
#pragma unroll
            for (int tn = 0; tn < 4; tn++)
                acc[tm][tn] = __builtin_amdgcn_mfma_f32_16x16x32_bf16(
                    af[tm], bfr[tn], acc[tm][tn], 0, 0, 0);
    }

    // all waves done reading Ab before we overwrite it with f32 proj
    __syncthreads();

    float bias[4];
#pragma unroll
    for (int tn = 0; tn < 4; tn++) bias[tn] = b[t * 64 + tn * 16 + m16];

    float* proj = reinterpret_cast<float*>(&Ab[0][0]);   // [128][68] f32, stride 68
#pragma unroll
    for (int tm = 0; tm < 2; tm++) {
#pragma unroll
        for (int r = 0; r < 4; r++) {
            const int eloc = wv * 32 + tm * 16 + quad * 4 + r;   // in [wv*32, wv*32+32)
            const float s = scale_s[eloc];
#pragma unroll
            for (int tn = 0; tn < 4; tn++) {
                float v = acc[tm][tn][r] + bias[tn];
                v = v > 0.f ? v : 0.f;
                proj[eloc * 68 + tn * 16 + m16] = v * s;
            }
        }
    }
    // NO barrier: wave wv wrote exactly proj rows [wv*32, wv*32+32) and reads
    // only those below. (src_s/scale_s were synced by the earlier barrier.)

    // wave-cooperative segmented reduce: lane = feature, walk 32 sorted edges,
    // flush one COALESCED 256B atomic burst per segment (R1-fast atomic pattern;
    // R3's per-lane scattered atomics were the 1 GB WRITE_SIZE / 20x-slower path).
    {
        const int j0 = wv * 32;
        float sum = 0.f;
#pragma unroll
        for (int j = j0; j < j0 + 32; j++) {
            sum += proj[j * 68 + lane];
            const bool flush = (j == j0 + 31) || (src_s[j + 1] != src_s[j]);
            if (flush) {
                atomicAdd(out + (size_t)src_s[j] * 64 + lane, sum);
                sum = 0.f;
            }
        }
    }
}

extern "C" void kernel_launch(void* const* d_in, const int* in_sizes, int n_in,
                              void* d_out, int out_size, void* d_ws, size_t ws_size,
                              hipStream_t stream) {
    const float* x     = (const float*)d_in[0];
    const float* W     = (const float*)d_in[1];
    const float* b     = (const float*)d_in[2];
    const float* ea    = (const float*)d_in[3];
    const int*   edges = (const int*)d_in[4];
    float* out = (float*)d_out;

    char* ws = (char*)d_ws;
    unsigned short* xbf = (unsigned short*)(ws + OFF_XBF);
    unsigned short* wT  = (unsigned short*)(ws + OFF_WT);
    unsigned* counts    = (unsigned*)(ws + OFF_CNT);
    float* wgt          = (float*)(ws + OFF_WGT);
    unsigned* cur       = (unsigned*)(ws + OFF_CUR);
    unsigned* bsum      = (unsigned*)(ws + OFF_BS);
    unsigned* boff      = (unsigned*)(ws + OFF_BO);
    int2* sorted        = (int2*)(ws + OFF_SRT);
    float* scl          = (float*)(ws + OFF_SCL);

    // Phase 1: out-zero, x->bf16, counts-zero, W^T, softmax
    k_init<<<(NN * DD) / 256, 256, 0, stream>>>(x, W, ea, xbf, wT, counts, wgt, out);

    // Phase 2: degree counts
    k_count<<<(TT * EE + 255) / 256, 256, 0, stream>>>(edges, counts);

    // Phase 2b: exclusive scan counts -> cur
    k_scan1<<<SCAN_B, SCAN_T, 0, stream>>>(counts, cur, bsum);
    k_scan2<<<1, SCAN_B, 0, stream>>>(bsum, boff);
    k_scan3<<<SCAN_B, SCAN_T, 0, stream>>>(cur, boff);

    // Phase 2c: counting-sort edges by (t, src)
    k_fill<<<(TT * EE + 255) / 256, 256, 0, stream>>>(edges, cur, counts, wgt, sorted, scl);

    // Phase 3: MFMA gather-GEMM + wave-cooperative segmented scatter
    dim3 grid(EE / 128, TT);
    k_edge<<<grid, 256, 0, stream>>>(xbf, wT, b, sorted, scl, out);
}